// Round 11
// baseline (217.382 us; speedup 1.0000x reference)
//
#include <hip/hip_runtime.h>

#define S 2048
#define D 1024
#define NH 16
#define HD 64
#define N3 3072         // 3 * D
#define M 4096          // T * B

typedef short s16x8 __attribute__((ext_vector_type(8)));
typedef _Float16 f16x8 __attribute__((ext_vector_type(8)));
typedef float f32x4 __attribute__((ext_vector_type(4)));
typedef float f32x16 __attribute__((ext_vector_type(16)));
typedef unsigned int u32;
typedef u32 u32x4 __attribute__((ext_vector_type(4)));

#define LOG2E 1.44269504088896340736f

__device__ __forceinline__ unsigned short f2bf(float f) {
  unsigned u = __builtin_bit_cast(unsigned, f);
  u += 0x7fffu + ((u >> 16) & 1u);
  return (unsigned short)(u >> 16);
}
__device__ __forceinline__ float bf2f(unsigned short h) {
  return __builtin_bit_cast(float, (unsigned)h << 16);
}
__device__ __forceinline__ unsigned short f2h(float f) {
  _Float16 h = (_Float16)f;
  return __builtin_bit_cast(unsigned short, h);
}

__device__ __forceinline__ float wsum(float v) {
  #pragma unroll
  for (int m = 1; m < 64; m <<= 1) v += __shfl_xor(v, m, 64);
  return v;
}

__device__ __forceinline__ void gload_lds16(const unsigned short* g, unsigned short* l) {
  __builtin_amdgcn_global_load_lds(
      (const __attribute__((address_space(1))) u32*)g,
      (__attribute__((address_space(3))) u32*)l, 16, 0, 0);
}
__device__ __forceinline__ void gload_lds4(const float* g, float* l) {
  __builtin_amdgcn_global_load_lds(
      (const __attribute__((address_space(1))) u32*)g,
      (__attribute__((address_space(3))) u32*)l, 4, 0, 0);
}

// ---------------------------------------------------------------------------
// Kernel 0: split f32 -> 2x fp16 limbs (verified r4).
// ---------------------------------------------------------------------------
__global__ __launch_bounds__(256) void split_k(const float* __restrict__ q,
                                               const float* __restrict__ w,
                                               unsigned short* __restrict__ A1,
                                               unsigned short* __restrict__ A2,
                                               unsigned short* __restrict__ W1,
                                               unsigned short* __restrict__ W2) {
  const size_t gid = (size_t)blockIdx.x * 256 + threadIdx.x;   // quad index
  const size_t NA = (size_t)M * D / 4;                          // 1048576
  float4 x;
  unsigned short* p1; unsigned short* p2; size_t qi; float scale;
  if (gid < NA) {
    qi = gid;  x = ((const float4*)q)[qi];
    p1 = A1; p2 = A2; scale = 64.f;
  } else {
    qi = gid - NA;  x = ((const float4*)w)[qi];
    p1 = W1; p2 = W2; scale = 1024.f;
  }
  float e[4] = {x.x * scale, x.y * scale, x.z * scale, x.w * scale};
  unsigned short h1[4], h2[4];
  #pragma unroll
  for (int i = 0; i < 4; ++i) {
    _Float16 a = (_Float16)e[i];
    float r = e[i] - (float)a;
    _Float16 b = (_Float16)r;
    h1[i] = __builtin_bit_cast(unsigned short, a);
    h2[i] = __builtin_bit_cast(unsigned short, b);
  }
  *(ushort4*)&p1[qi * 4] = make_ushort4(h1[0], h1[1], h1[2], h1[3]);
  *(ushort4*)&p2[qi * 4] = make_ushort4(h2[0], h2[1], h2[2], h2[3]);
}

// ---------------------------------------------------------------------------
// Kernel 1: emulated-f32 GEMM on fp16 MFMA (verified r4, unchanged).
// ---------------------------------------------------------------------------
__global__ __launch_bounds__(256) void gemm_mfma(const unsigned short* __restrict__ A1,
                                                 const unsigned short* __restrict__ A2,
                                                 const unsigned short* __restrict__ W1,
                                                 const unsigned short* __restrict__ W2,
                                                 const float* __restrict__ bias,
                                                 float* __restrict__ C) {
  __shared__ unsigned short As[128 * 64];
  __shared__ unsigned short Bs[128 * 64];
  const int tid = threadIdx.x;
  const int w = tid >> 6, l = tid & 63;
  const int lo = l & 15, hi = l >> 4;
  const int n0 = blockIdx.x * 128, m0 = blockIdx.y * 128;
  const int wr = w >> 1, wc = w & 1;          // wave tile 64x64

  const int nseg = (n0 >= 2048) ? 1 : 3;

  const int srow = (tid >> 3) & 31;
  const int skc = tid & 7;

  f32x4 acc[4][4];
  #pragma unroll
  for (int mi = 0; mi < 4; ++mi)
    #pragma unroll
    for (int nj = 0; nj < 4; ++nj) acc[mi][nj] = (f32x4){0.f, 0.f, 0.f, 0.f};

  for (int s = 0; s < 3; ++s) {
    if (s >= nseg) break;
    const unsigned short* Ab;
    const unsigned short* Bb;
    switch (s) {                               // uniform scalar branch
      case 0: Ab = A1; Bb = W1; break;
      case 1: Ab = A2; Bb = W1; break;
      default: Ab = A1; Bb = W2; break;
    }
    Ab += (size_t)m0 * D;
    Bb += (size_t)n0 * D;

    for (int k0 = 0; k0 < D; k0 += 64) {
      __syncthreads();                         // prior iter's LDS reads done
      #pragma unroll
      for (int c = 0; c < 4; ++c) {
        const int row = c * 32 + srow;
        const int koct = skc ^ (row & 7);      // pre-swizzled source
        gload_lds16(Ab + (size_t)row * D + k0 + koct * 8,
                    As + c * 2048 + w * 512);
        gload_lds16(Bb + (size_t)row * D + k0 + koct * 8,
                    Bs + c * 2048 + w * 512);
      }
      __syncthreads();

      f16x8 af[4][2], bf[4][2];
      #pragma unroll
      for (int mi = 0; mi < 4; ++mi)
        #pragma unroll
        for (int ks = 0; ks < 2; ++ks) {
          const int row = wr * 64 + mi * 16 + lo;
          const int koct = (ks * 4 + hi) ^ (lo & 7);
          af[mi][ks] = *(const f16x8*)&As[row * 64 + koct * 8];
        }
      #pragma unroll
      for (int nj = 0; nj < 4; ++nj)
        #pragma unroll
        for (int ks = 0; ks < 2; ++ks) {
          const int row = wc * 64 + nj * 16 + lo;
          const int koct = (ks * 4 + hi) ^ (lo & 7);
          bf[nj][ks] = *(const f16x8*)&Bs[row * 64 + koct * 8];
        }
      #pragma unroll
      for (int mi = 0; mi < 4; ++mi)
        #pragma unroll
        for (int nj = 0; nj < 4; ++nj)
          #pragma unroll
          for (int ks = 0; ks < 2; ++ks)
            acc[mi][nj] = __builtin_amdgcn_mfma_f32_16x16x32_f16(
                af[mi][ks], bf[nj][ks], acc[mi][nj], 0, 0, 0);
    }
  }

  #pragma unroll
  for (int mi = 0; mi < 4; ++mi)
    #pragma unroll
    for (int nj = 0; nj < 4; ++nj) {
      const int n = n0 + wc * 64 + nj * 16 + lo;
      const float bj = bias[n];
      #pragma unroll
      for (int r = 0; r < 4; ++r) {
        const int m = m0 + wr * 64 + mi * 16 + hi * 4 + r;
        C[(size_t)m * N3 + n] = acc[mi][nj][r] * (1.f / 65536.f) + bj;
      }
    }
}

// ---------------------------------------------------------------------------
// Kernel 2: per-row stats + layout conversion (r10 numerics, verified
// absmax 9.77e-4): rs pre-scaled by sqrt(log2e) for exp2-direct softmax.
// ---------------------------------------------------------------------------
__global__ __launch_bounds__(256) void stats_k(const float* __restrict__ qkv,
                                               unsigned short* __restrict__ qhi,
                                               unsigned short* __restrict__ qlo,
                                               unsigned short* __restrict__ khi,
                                               unsigned short* __restrict__ klo,
                                               unsigned short* __restrict__ vt,
                                               float* __restrict__ rs) {
  __shared__ unsigned short VsT[64][65];
  const int tt = blockIdx.x, bh = blockIdx.y;
  const int b = bh >> 4, h = bh & 15;
  const int w = threadIdx.x >> 6, l = threadIdx.x & 63;

  for (int rr = 0; rr < 16; ++rr) {
    const int t = tt * 64 + w * 16 + rr;
    const size_t base = (size_t)(t * 2 + b) * N3 + h * HD;
    const float q = qkv[base + l];
    const float k = qkv[base + D + l];
    const float v = qkv[base + 2 * D + l];
    const float qm = wsum(q) * (1.f / 64.f);
    const float km = wsum(k) * (1.f / 64.f);
    const float qcv = q - qm, kcv = k - km;
    const float d = wsum(qcv * kcv);
    float rv = 0.f;
    if (d > 0.f) {
      rv = rsqrtf(d);
      rv = rv * (1.5f - 0.5f * d * rv * rv);   // one NR step
      rv *= 1.20112240872f;                    // sqrt(log2e): exp2 fold
    }
    const size_t ro = ((size_t)bh * S + t) * HD + l;
    const unsigned short qh = f2bf(qcv);
    const unsigned short kh = f2bf(kcv);
    qhi[ro] = qh;  qlo[ro] = f2bf(qcv - bf2f(qh));
    khi[ro] = kh;  klo[ro] = f2bf(kcv - bf2f(kh));
    if (l == 0) rs[(size_t)bh * S + t] = rv;
    VsT[l][w * 16 + rr] = f2h(v);              // fp16 V
  }
  __syncthreads();
  const int dd = threadIdx.x >> 2, seg = threadIdx.x & 3;
  unsigned pk[8];
  #pragma unroll
  for (int e = 0; e < 8; ++e) {
    unsigned l2 = VsT[dd][seg * 16 + 2 * e];
    unsigned h2 = VsT[dd][seg * 16 + 2 * e + 1];
    pk[e] = l2 | (h2 << 16);
  }
  unsigned short* dst = vt + ((size_t)bh * HD + dd) * S + tt * 64 + seg * 16;
  *(uint4*)dst       = make_uint4(pk[0], pk[1], pk[2], pk[3]);
  *(uint4*)(dst + 8) = make_uint4(pk[4], pk[5], pk[6], pk[7]);
}

// ---------------------------------------------------------------------------
// Kernel 3: fused correlation-softmax-PV, 32x32x16 swapped QK^T (r9 verified
// compute body) + r11: IN-BLOCK KV-SPLIT-2. 512 thr / 8 waves: waves 0-3
// handle j in [0,1024), waves 4-7 j in [1024,2048), private tile-sets
// (buf = half). Same per-wave geometry as r9, 2x the waves/CU (8 -> 16,
// the only lever that has ever moved this kernel: r6). Cross-half merge is
// an in-LDS epilogue (stride-33 padded -> conflict-free); no global
// partials, no combine kernel (r8's overhead).
// ---------------------------------------------------------------------------
__global__ __launch_bounds__(512, 4) void attn_k(const unsigned short* __restrict__ qhi,
                                                 const unsigned short* __restrict__ qlo,
                                                 const unsigned short* __restrict__ khi,
                                                 const unsigned short* __restrict__ klo,
                                                 const unsigned short* __restrict__ vt,
                                                 const float* __restrict__ rs,
                                                 float* __restrict__ out) {
  __shared__ __align__(16) char smem[49664];
  unsigned short* Kh = (unsigned short*)smem;            // [2][4096] shorts
  unsigned short* Kl = (unsigned short*)(smem + 16384);  // [2][4096]
  unsigned short* Vs = (unsigned short*)(smem + 32768);  // [2][4096]
  float* Rsl = (float*)(smem + 49152);                   // [2][64]

  const int tid = threadIdx.x;
  const int w = tid >> 6, l = tid & 63;
  const int wq = w & 3;                    // q-wave within half
  const int wh = w >> 2;                   // kv-half
  const int lq = l & 31, h = l >> 5, l7 = l & 7;

  // T1: XCD-aware swizzle (512 = 8 XCD x 64, exact -> bijective).
  const int wgid = blockIdx.x;
  const int orig = (wgid & 7) * 64 + (wgid >> 3);
  const int bh = orig >> 4, qt = orig & 15;

  const unsigned short* qhb = qhi + (size_t)bh * S * HD;
  const unsigned short* qlb = qlo + (size_t)bh * S * HD;
  const unsigned short* khb = khi + (size_t)bh * S * HD;
  const unsigned short* klb = klo + (size_t)bh * S * HD;
  const unsigned short* vbase = vt + (size_t)bh * HD * S;
  const float* rbase = rs + (size_t)bh * S;
  const int qrow0 = qt * 128 + wq * 32;    // wave owns 32 q-rows

  // staging map (within half, 4 waves stage 64 rows x 128B)
  const int srow3 = l >> 3;                // 0..7
  const int sg = l7 ^ srow3;               // pre-swizzled source granule

  // Q fragments (B-operand): lane holds q-row qrow0+lq, d-chunk kc*16+h*8
  s16x8 qfh[4], qfl[4];
  #pragma unroll
  for (int kc = 0; kc < 4; ++kc) {
    const size_t off = (size_t)(qrow0 + lq) * HD + kc * 16 + h * 8;
    qfh[kc] = *(const s16x8*)(qhb + off);
    qfl[kc] = *(const s16x8*)(qlb + off);
  }
  const float rsq = rbase[qrow0 + lq];     // lane-local row scale (q = lq)

  f32x16 oacc[2];
  oacc[0] = (f32x16)(0.f);
  oacc[1] = (f32x16)(0.f);
  float den = 0.f;

  const int hb = wh * 4096;                // half's plane base (shorts)
  const int jbeg = wh * 1024;

  for (int t = 0; t < 16; ++t) {
    const int j0 = jbeg + t * 64;
    __syncthreads();                       // prior iter's LDS reads done
    #pragma unroll
    for (int c = 0; c < 2; ++c) {
      const int row = c * 32 + wq * 8 + srow3;
      const int dst = hb + c * 2048 + wq * 512;   // wave-uniform LDS base
      gload_lds16(khb + (size_t)(j0 + row) * HD + sg * 8, Kh + dst);
      gload_lds16(klb + (size_t)(j0 + row) * HD + sg * 8, Kl + dst);
      gload_lds16(vbase + (size_t)row * S + j0 + sg * 8, Vs + dst);
    }
    if (wq == 0) gload_lds4(rbase + j0 + l, Rsl + wh * 64);
    __syncthreads();                       // vmcnt(0) drain + barrier

    #pragma unroll
    for (int jblk = 0; jblk < 2; ++jblk) {
      // swapped QK^T: sacc[r] = S[j = j0+jblk*32+(r&3)+8*(r>>2)+4h][q = lq]
      f32x16 sacc = (f32x16)(0.f);
      #pragma unroll
      for (int kc = 0; kc < 4; ++kc) {
        const int off = hb + (jblk * 32 + lq) * 64 + (((kc * 2 + h) ^ l7) << 3);
        s16x8 akh = *(const s16x8*)&Kh[off];
        s16x8 akl = *(const s16x8*)&Kl[off];
        sacc = __builtin_amdgcn_mfma_f32_32x32x16_bf16(akh, qfh[kc], sacc, 0, 0, 0);
        sacc = __builtin_amdgcn_mfma_f32_32x32x16_bf16(akl, qfh[kc], sacc, 0, 0, 0);
        sacc = __builtin_amdgcn_mfma_f32_32x32x16_bf16(akh, qfl[kc], sacc, 0, 0, 0);
      }

      // softmax elements + fp16 packs; e = exp2(clip(t, +-log2e)), pre-scaled
      u32 pkA[4], pkB[4];
      #pragma unroll
      for (int g = 0; g < 4; ++g) {
        f32x4 rjv = *(const f32x4*)&Rsl[wh * 64 + jblk * 32 + g * 8 + h * 4];
        float e0, e1, e2, e3;
        {
          float t0 = fminf(LOG2E, fmaxf(-LOG2E, sacc[4 * g + 0] * rsq * rjv[0]));
          float t1 = fminf(LOG2E, fmaxf(-LOG2E, sacc[4 * g + 1] * rsq * rjv[1]));
          float t2 = fminf(LOG2E, fmaxf(-LOG2E, sacc[4 * g + 2] * rsq * rjv[2]));
          float t3 = fminf(LOG2E, fmaxf(-LOG2E, sacc[4 * g + 3] * rsq * rjv[3]));
          e0 = exp2f(t0); e1 = exp2f(t1); e2 = exp2f(t2); e3 = exp2f(t3);
        }
        den += (e0 + e1) + (e2 + e3);
        pkA[g] = __builtin_bit_cast(u32, __builtin_amdgcn_cvt_pkrtz(e0, e1));
        pkB[g] = __builtin_bit_cast(u32, __builtin_amdgcn_cvt_pkrtz(e2, e3));
      }

      // P A-frags per k-chunk jc2 (j = (jblk*2+jc2)*16 + h*8 + 0..7)
      #pragma unroll
      for (int jc2 = 0; jc2 < 2; ++jc2) {
        const u32 sA = h ? pkA[2 * jc2] : pkA[2 * jc2 + 1];
        const u32 sB = h ? pkB[2 * jc2] : pkB[2 * jc2 + 1];
        const u32 rA = (u32)__shfl_xor((int)sA, 32, 64);
        const u32 rB = (u32)__shfl_xor((int)sB, 32, 64);
        u32x4 uu;
        uu[0] = h ? rA : pkA[2 * jc2];         // e0,e1 (low lane's group)
        uu[1] = h ? rB : pkB[2 * jc2];         // e2,e3
        uu[2] = h ? pkA[2 * jc2 + 1] : rA;     // e4,e5 (high lane's group)
        uu[3] = h ? pkB[2 * jc2 + 1] : rB;     // e6,e7
        const f16x8 pa = __builtin_bit_cast(f16x8, uu);

        const int jcg = jblk * 2 + jc2;
        #pragma unroll
        for (int dblk = 0; dblk < 2; ++dblk) {
          const int voff = hb + (dblk * 32 + lq) * 64 + (((jcg * 2 + h) ^ l7) << 3);
          f16x8 bv = *(const f16x8*)&Vs[voff];
          oacc[dblk] = __builtin_amdgcn_mfma_f32_32x32x16_f16(pa, bv, oacc[dblk], 0, 0, 0);
        }
      }
    }
  }

  // half-local den total for q = lq (sum the two h-partials)
  const float dhalf = den + __shfl_xor(den, 32, 64);

  // cross-half combine via LDS (tiles dead; stride-33 pad -> conflict-free)
  __syncthreads();
  float* csum = (float*)smem;                  // [4][64][33] floats
  float* cden = (float*)(smem + 33792);        // [4][32]
  if (wh == 1) {
    const int base = (wq * 64 + l) * 33;
    #pragma unroll
    for (int r = 0; r < 16; ++r) {
      csum[base + r]      = oacc[0][r];
      csum[base + 16 + r] = oacc[1][r];
    }
    if (l < 32) cden[wq * 32 + lq] = dhalf;
  }
  __syncthreads();
  if (wh == 0) {
    const float dtot = dhalf + cden[wq * 32 + lq];
    const float inv = 1.f / dtot;              // valid for q = lq
    const int base = (wq * 64 + l) * 33;
    #pragma unroll
    for (int r = 0; r < 16; ++r) {
      oacc[0][r] += csum[base + r];
      oacc[1][r] += csum[base + 16 + r];
    }
    #pragma unroll
    for (int g = 0; g < 4; ++g)
      #pragma unroll
      for (int i = 0; i < 4; ++i) {
        const int qr = i + 8 * g + 4 * h;      // C-row for reg r = 4g+i
        const float invq = __shfl(inv, i + 8 * g + 4 * h, 64);
        const size_t row = (size_t)bh * S + qrow0 + qr;
        out[row * HD + lq]      = oacc[0][4 * g + i] * invq;
        out[row * HD + 32 + lq] = oacc[1][4 * g + i] * invq;
      }
  }
}

extern "C" void kernel_launch(void* const* d_in, const int* in_sizes, int n_in,
                              void* d_out, int out_size, void* d_ws, size_t ws_size,
                              hipStream_t stream) {
  const float* query = (const float*)d_in[0];
  const float* W     = (const float*)d_in[1];
  const float* bias  = (const float*)d_in[2];
  float* out = (float*)d_out;
  char* ws = (char*)d_ws;

  float*          qkv = (float*)ws;                          // dead after stats_k
  // fp16 split planes live only between split_k and gemm_mfma:
  unsigned short* A1 = (unsigned short*)(ws + 50331648);
  unsigned short* A2 = (unsigned short*)(ws + 58720256);
  unsigned short* W1 = (unsigned short*)(ws + 67108864);
  unsigned short* W2 = (unsigned short*)(ws + 73400320);
  // stats outputs reuse the (dead) split region:
  unsigned short* qhi = (unsigned short*)(ws + 50331648);
  unsigned short* qlo = (unsigned short*)(ws + 58720256);
  unsigned short* khi = (unsigned short*)(ws + 67108864);
  unsigned short* klo = (unsigned short*)(ws + 75497472);
  unsigned short* vt  = (unsigned short*)(ws + 83886080);
  float*          rsb = (float*)(ws + 92274688);

  split_k  <<<dim3(7168), 256, 0, stream>>>(query, W, A1, A2, W1, W2);
  gemm_mfma<<<dim3(24, 32), 256, 0, stream>>>(A1, A2, W1, W2, bias, qkv);
  stats_k  <<<dim3(32, 32), 256, 0, stream>>>(qkv, qhi, qlo, khi, klo, vt, rsb);
  attn_k   <<<dim3(512), 512, 0, stream>>>(qhi, qlo, khi, klo, vt, rsb, out);
}

// Round 12
// 190.430 us; speedup vs baseline: 1.1415x; 1.1415x over previous
//
#include <hip/hip_runtime.h>

#define S 2048
#define D 1024
#define NH 16
#define HD 64
#define N3 3072         // 3 * D
#define M 4096          // T * B

typedef short s16x8 __attribute__((ext_vector_type(8)));
typedef _Float16 f16x8 __attribute__((ext_vector_type(8)));
typedef float f32x4 __attribute__((ext_vector_type(4)));
typedef float f32x16 __attribute__((ext_vector_type(16)));
typedef unsigned int u32;
typedef u32 u32x4 __attribute__((ext_vector_type(4)));

#define LOG2E 1.44269504088896340736f

__device__ __forceinline__ unsigned short f2bf(float f) {
  unsigned u = __builtin_bit_cast(unsigned, f);
  u += 0x7fffu + ((u >> 16) & 1u);
  return (unsigned short)(u >> 16);
}
__device__ __forceinline__ float bf2f(unsigned short h) {
  return __builtin_bit_cast(float, (unsigned)h << 16);
}
__device__ __forceinline__ unsigned short f2h(float f) {
  _Float16 h = (_Float16)f;
  return __builtin_bit_cast(unsigned short, h);
}

__device__ __forceinline__ float wsum(float v) {
  #pragma unroll
  for (int m = 1; m < 64; m <<= 1) v += __shfl_xor(v, m, 64);
  return v;
}

__device__ __forceinline__ void gload_lds16(const unsigned short* g, unsigned short* l) {
  __builtin_amdgcn_global_load_lds(
      (const __attribute__((address_space(1))) u32*)g,
      (__attribute__((address_space(3))) u32*)l, 16, 0, 0);
}
__device__ __forceinline__ void gload_lds4(const float* g, float* l) {
  __builtin_amdgcn_global_load_lds(
      (const __attribute__((address_space(1))) u32*)g,
      (__attribute__((address_space(3))) u32*)l, 4, 0, 0);
}

// ---------------------------------------------------------------------------
// Kernel 0: split f32 -> 2x fp16 limbs (verified r4).
// ---------------------------------------------------------------------------
__global__ __launch_bounds__(256) void split_k(const float* __restrict__ q,
                                               const float* __restrict__ w,
                                               unsigned short* __restrict__ A1,
                                               unsigned short* __restrict__ A2,
                                               unsigned short* __restrict__ W1,
                                               unsigned short* __restrict__ W2) {
  const size_t gid = (size_t)blockIdx.x * 256 + threadIdx.x;   // quad index
  const size_t NA = (size_t)M * D / 4;                          // 1048576
  float4 x;
  unsigned short* p1; unsigned short* p2; size_t qi; float scale;
  if (gid < NA) {
    qi = gid;  x = ((const float4*)q)[qi];
    p1 = A1; p2 = A2; scale = 64.f;
  } else {
    qi = gid - NA;  x = ((const float4*)w)[qi];
    p1 = W1; p2 = W2; scale = 1024.f;
  }
  float e[4] = {x.x * scale, x.y * scale, x.z * scale, x.w * scale};
  unsigned short h1[4], h2[4];
  #pragma unroll
  for (int i = 0; i < 4; ++i) {
    _Float16 a = (_Float16)e[i];
    float r = e[i] - (float)a;
    _Float16 b = (_Float16)r;
    h1[i] = __builtin_bit_cast(unsigned short, a);
    h2[i] = __builtin_bit_cast(unsigned short, b);
  }
  *(ushort4*)&p1[qi * 4] = make_ushort4(h1[0], h1[1], h1[2], h1[3]);
  *(ushort4*)&p2[qi * 4] = make_ushort4(h2[0], h2[1], h2[2], h2[3]);
}

// ---------------------------------------------------------------------------
// Kernel 1: emulated-f32 GEMM on fp16 MFMA (verified r4, unchanged).
// ---------------------------------------------------------------------------
__global__ __launch_bounds__(256) void gemm_mfma(const unsigned short* __restrict__ A1,
                                                 const unsigned short* __restrict__ A2,
                                                 const unsigned short* __restrict__ W1,
                                                 const unsigned short* __restrict__ W2,
                                                 const float* __restrict__ bias,
                                                 float* __restrict__ C) {
  __shared__ unsigned short As[128 * 64];
  __shared__ unsigned short Bs[128 * 64];
  const int tid = threadIdx.x;
  const int w = tid >> 6, l = tid & 63;
  const int lo = l & 15, hi = l >> 4;
  const int n0 = blockIdx.x * 128, m0 = blockIdx.y * 128;
  const int wr = w >> 1, wc = w & 1;          // wave tile 64x64

  const int nseg = (n0 >= 2048) ? 1 : 3;

  const int srow = (tid >> 3) & 31;
  const int skc = tid & 7;

  f32x4 acc[4][4];
  #pragma unroll
  for (int mi = 0; mi < 4; ++mi)
    #pragma unroll
    for (int nj = 0; nj < 4; ++nj) acc[mi][nj] = (f32x4){0.f, 0.f, 0.f, 0.f};

  for (int s = 0; s < 3; ++s) {
    if (s >= nseg) break;
    const unsigned short* Ab;
    const unsigned short* Bb;
    switch (s) {                               // uniform scalar branch
      case 0: Ab = A1; Bb = W1; break;
      case 1: Ab = A2; Bb = W1; break;
      default: Ab = A1; Bb = W2; break;
    }
    Ab += (size_t)m0 * D;
    Bb += (size_t)n0 * D;

    for (int k0 = 0; k0 < D; k0 += 64) {
      __syncthreads();                         // prior iter's LDS reads done
      #pragma unroll
      for (int c = 0; c < 4; ++c) {
        const int row = c * 32 + srow;
        const int koct = skc ^ (row & 7);      // pre-swizzled source
        gload_lds16(Ab + (size_t)row * D + k0 + koct * 8,
                    As + c * 2048 + w * 512);
        gload_lds16(Bb + (size_t)row * D + k0 + koct * 8,
                    Bs + c * 2048 + w * 512);
      }
      __syncthreads();

      f16x8 af[4][2], bf[4][2];
      #pragma unroll
      for (int mi = 0; mi < 4; ++mi)
        #pragma unroll
        for (int ks = 0; ks < 2; ++ks) {
          const int row = wr * 64 + mi * 16 + lo;
          const int koct = (ks * 4 + hi) ^ (lo & 7);
          af[mi][ks] = *(const f16x8*)&As[row * 64 + koct * 8];
        }
      #pragma unroll
      for (int nj = 0; nj < 4; ++nj)
        #pragma unroll
        for (int ks = 0; ks < 2; ++ks) {
          const int row = wc * 64 + nj * 16 + lo;
          const int koct = (ks * 4 + hi) ^ (lo & 7);
          bf[nj][ks] = *(const f16x8*)&Bs[row * 64 + koct * 8];
        }
      #pragma unroll
      for (int mi = 0; mi < 4; ++mi)
        #pragma unroll
        for (int nj = 0; nj < 4; ++nj)
          #pragma unroll
          for (int ks = 0; ks < 2; ++ks)
            acc[mi][nj] = __builtin_amdgcn_mfma_f32_16x16x32_f16(
                af[mi][ks], bf[nj][ks], acc[mi][nj], 0, 0, 0);
    }
  }

  #pragma unroll
  for (int mi = 0; mi < 4; ++mi)
    #pragma unroll
    for (int nj = 0; nj < 4; ++nj) {
      const int n = n0 + wc * 64 + nj * 16 + lo;
      const float bj = bias[n];
      #pragma unroll
      for (int r = 0; r < 4; ++r) {
        const int m = m0 + wr * 64 + mi * 16 + hi * 4 + r;
        C[(size_t)m * N3 + n] = acc[mi][nj][r] * (1.f / 65536.f) + bj;
      }
    }
}

// ---------------------------------------------------------------------------
// Kernel 2: per-row stats + layout conversion (r10 numerics, verified
// absmax 9.77e-4): unfolded bf16 2-limb qc/kc; rs pre-scaled by sqrt(log2e)
// for exp2-direct softmax; fp16 V.
// ---------------------------------------------------------------------------
__global__ __launch_bounds__(256) void stats_k(const float* __restrict__ qkv,
                                               unsigned short* __restrict__ qhi,
                                               unsigned short* __restrict__ qlo,
                                               unsigned short* __restrict__ khi,
                                               unsigned short* __restrict__ klo,
                                               unsigned short* __restrict__ vt,
                                               float* __restrict__ rs) {
  __shared__ unsigned short VsT[64][65];
  const int tt = blockIdx.x, bh = blockIdx.y;
  const int b = bh >> 4, h = bh & 15;
  const int w = threadIdx.x >> 6, l = threadIdx.x & 63;

  for (int rr = 0; rr < 16; ++rr) {
    const int t = tt * 64 + w * 16 + rr;
    const size_t base = (size_t)(t * 2 + b) * N3 + h * HD;
    const float q = qkv[base + l];
    const float k = qkv[base + D + l];
    const float v = qkv[base + 2 * D + l];
    const float qm = wsum(q) * (1.f / 64.f);
    const float km = wsum(k) * (1.f / 64.f);
    const float qcv = q - qm, kcv = k - km;
    const float d = wsum(qcv * kcv);
    float rv = 0.f;
    if (d > 0.f) {
      rv = rsqrtf(d);
      rv = rv * (1.5f - 0.5f * d * rv * rv);   // one NR step
      rv *= 1.20112240872f;                    // sqrt(log2e): exp2 fold
    }
    const size_t ro = ((size_t)bh * S + t) * HD + l;
    const unsigned short qh = f2bf(qcv);
    const unsigned short kh = f2bf(kcv);
    qhi[ro] = qh;  qlo[ro] = f2bf(qcv - bf2f(qh));
    khi[ro] = kh;  klo[ro] = f2bf(kcv - bf2f(kh));
    if (l == 0) rs[(size_t)bh * S + t] = rv;
    VsT[l][w * 16 + rr] = f2h(v);              // fp16 V
  }
  __syncthreads();
  const int dd = threadIdx.x >> 2, seg = threadIdx.x & 3;
  unsigned pk[8];
  #pragma unroll
  for (int e = 0; e < 8; ++e) {
    unsigned l2 = VsT[dd][seg * 16 + 2 * e];
    unsigned h2 = VsT[dd][seg * 16 + 2 * e + 1];
    pk[e] = l2 | (h2 << 16);
  }
  unsigned short* dst = vt + ((size_t)bh * HD + dd) * S + tt * 64 + seg * 16;
  *(uint4*)dst       = make_uint4(pk[0], pk[1], pk[2], pk[3]);
  *(uint4*)(dst + 8) = make_uint4(pk[4], pk[5], pk[6], pk[7]);
}

// ---------------------------------------------------------------------------
// Kernel 3: fused correlation-softmax-PV, 32x32x16 swapped QK^T.
// r12 = r9's verified structure with BK 64 -> 128: same bytes staged, same
// swizzle algebra (V kept as two 64-wide tiles so every LDS access pattern
// is byte-identical to r9's), but HALF the iterations -> half the
// barrier-drain stalls (the remaining unexplained ~50% of r9's runtime).
// Monolithic KV loop (no split: r8/r11 falsified), 256 thr, grid 512.
// ---------------------------------------------------------------------------
__global__ __launch_bounds__(256) void attn_k(const unsigned short* __restrict__ qhi,
                                              const unsigned short* __restrict__ qlo,
                                              const unsigned short* __restrict__ khi,
                                              const unsigned short* __restrict__ klo,
                                              const unsigned short* __restrict__ vt,
                                              const float* __restrict__ rs,
                                              float* __restrict__ out) {
  __shared__ unsigned short Kh[128 * 64];  // [row j][64 d], XOR-granule
  __shared__ unsigned short Kl[128 * 64];
  __shared__ unsigned short Vs0[64 * 64];  // [row d][64 j], j in [j0, j0+64)
  __shared__ unsigned short Vs1[64 * 64];  // [row d][64 j], j in [j0+64, ..)
  __shared__ float Rsl[128];

  const int tid = threadIdx.x;
  const int w = tid >> 6, l = tid & 63;
  const int lq = l & 31;                   // col q / A-row index
  const int h = l >> 5;                    // k-half selector
  const int l7 = l & 7;

  // T1: XCD-aware swizzle (512 = 8 XCD x 64, exact -> bijective).
  const int wgid = blockIdx.x;
  const int orig = (wgid & 7) * 64 + (wgid >> 3);
  const int bh = orig >> 4, qt = orig & 15;

  const unsigned short* qhb = qhi + (size_t)bh * S * HD;
  const unsigned short* qlb = qlo + (size_t)bh * S * HD;
  const unsigned short* khb = khi + (size_t)bh * S * HD;
  const unsigned short* klb = klo + (size_t)bh * S * HD;
  const unsigned short* vbase = vt + (size_t)bh * HD * S;
  const float* rbase = rs + (size_t)bh * S;
  const int qrow0 = qt * 128 + w * 32;     // wave owns 32 q-rows

  // staging map: linear LDS dest, pre-swizzled source (r9-verified)
  const int srow3 = l >> 3;                // 0..7 (row within wave's 8)
  const int sg = l7 ^ srow3;               // source granule

  // Q fragments (B-operand): lane holds q-row qrow0+lq, d-chunk kc*16+h*8
  s16x8 qfh[4], qfl[4];
  #pragma unroll
  for (int kc = 0; kc < 4; ++kc) {
    const size_t off = (size_t)(qrow0 + lq) * HD + kc * 16 + h * 8;
    qfh[kc] = *(const s16x8*)(qhb + off);
    qfl[kc] = *(const s16x8*)(qlb + off);
  }
  const float rsq = rbase[qrow0 + lq];     // lane-local row scale (q = lq)

  f32x16 oacc[2];
  oacc[0] = (f32x16)(0.f);
  oacc[1] = (f32x16)(0.f);
  float den = 0.f;

  for (int t = 0; t < 16; ++t) {
    const int j0 = t * 128;
    __syncthreads();                       // prior iter's LDS reads done
    #pragma unroll
    for (int c = 0; c < 4; ++c) {          // K planes: 128 j-rows
      const int row = c * 32 + w * 8 + srow3;
      const int dst = c * 2048 + w * 512;  // wave-uniform LDS base
      gload_lds16(khb + (size_t)(j0 + row) * HD + sg * 8, Kh + dst);
      gload_lds16(klb + (size_t)(j0 + row) * HD + sg * 8, Kl + dst);
    }
    #pragma unroll
    for (int c = 0; c < 2; ++c) {          // V: two 64-j tiles, 64 d-rows
      const int row = c * 32 + w * 8 + srow3;
      const int dst = c * 2048 + w * 512;
      gload_lds16(vbase + (size_t)row * S + j0 + sg * 8,      Vs0 + dst);
      gload_lds16(vbase + (size_t)row * S + j0 + 64 + sg * 8, Vs1 + dst);
    }
    if (w < 2) gload_lds4(rbase + j0 + w * 64 + l, Rsl + w * 64);
    __syncthreads();                       // vmcnt(0) drain + barrier

    #pragma unroll
    for (int jblk = 0; jblk < 4; ++jblk) {
      // swapped QK^T: sacc[r] = S[j = j0+jblk*32+(r&3)+8*(r>>2)+4h][q = lq]
      f32x16 sacc = (f32x16)(0.f);
      #pragma unroll
      for (int kc = 0; kc < 4; ++kc) {
        const int off = (jblk * 32 + lq) * 64 + (((kc * 2 + h) ^ l7) << 3);
        s16x8 akh = *(const s16x8*)&Kh[off];
        s16x8 akl = *(const s16x8*)&Kl[off];
        sacc = __builtin_amdgcn_mfma_f32_32x32x16_bf16(akh, qfh[kc], sacc, 0, 0, 0);
        sacc = __builtin_amdgcn_mfma_f32_32x32x16_bf16(akl, qfh[kc], sacc, 0, 0, 0);
        sacc = __builtin_amdgcn_mfma_f32_32x32x16_bf16(akh, qfl[kc], sacc, 0, 0, 0);
      }

      // softmax elements + fp16 packs; e = exp2(clip(t, +-log2e)), pre-scaled
      u32 pkA[4], pkB[4];
      #pragma unroll
      for (int g = 0; g < 4; ++g) {
        f32x4 rjv = *(const f32x4*)&Rsl[jblk * 32 + g * 8 + h * 4];
        float e0, e1, e2, e3;
        {
          float t0 = fminf(LOG2E, fmaxf(-LOG2E, sacc[4 * g + 0] * rsq * rjv[0]));
          float t1 = fminf(LOG2E, fmaxf(-LOG2E, sacc[4 * g + 1] * rsq * rjv[1]));
          float t2 = fminf(LOG2E, fmaxf(-LOG2E, sacc[4 * g + 2] * rsq * rjv[2]));
          float t3 = fminf(LOG2E, fmaxf(-LOG2E, sacc[4 * g + 3] * rsq * rjv[3]));
          e0 = exp2f(t0); e1 = exp2f(t1); e2 = exp2f(t2); e3 = exp2f(t3);
        }
        den += (e0 + e1) + (e2 + e3);
        pkA[g] = __builtin_bit_cast(u32, __builtin_amdgcn_cvt_pkrtz(e0, e1));
        pkB[g] = __builtin_bit_cast(u32, __builtin_amdgcn_cvt_pkrtz(e2, e3));
      }

      // P A-frags per k-chunk jc2 (j = j0 + (jblk*2+jc2)*16 + h*8 + 0..7)
      #pragma unroll
      for (int jc2 = 0; jc2 < 2; ++jc2) {
        const u32 sA = h ? pkA[2 * jc2] : pkA[2 * jc2 + 1];
        const u32 sB = h ? pkB[2 * jc2] : pkB[2 * jc2 + 1];
        const u32 rA = (u32)__shfl_xor((int)sA, 32, 64);
        const u32 rB = (u32)__shfl_xor((int)sB, 32, 64);
        u32x4 uu;
        uu[0] = h ? rA : pkA[2 * jc2];         // e0,e1 (low lane's group)
        uu[1] = h ? rB : pkB[2 * jc2];         // e2,e3
        uu[2] = h ? pkA[2 * jc2 + 1] : rA;     // e4,e5 (high lane's group)
        uu[3] = h ? pkB[2 * jc2 + 1] : rB;     // e6,e7
        const f16x8 pa = __builtin_bit_cast(f16x8, uu);

        const int jcg = jblk * 2 + jc2;        // 0..7 (16-j chunk in tile)
        const unsigned short* Vt = (jcg >= 4) ? Vs1 : Vs0;
        const int jl = jcg & 3;                // chunk within V tile
        #pragma unroll
        for (int dblk = 0; dblk < 2; ++dblk) {
          const int voff = (dblk * 32 + lq) * 64 + (((jl * 2 + h) ^ l7) << 3);
          f16x8 bv = *(const f16x8*)&Vt[voff];
          oacc[dblk] = __builtin_amdgcn_mfma_f32_32x32x16_f16(pa, bv, oacc[dblk], 0, 0, 0);
        }
      }
    }
  }

  // epilogue: den (this lane covers its h/reg j-subset; partner the rest)
  const float dtot = den + __shfl_xor(den, 32, 64);
  const float inv = 1.f / dtot;            // valid for q = lq (both halves)

  #pragma unroll
  for (int g = 0; g < 4; ++g)
    #pragma unroll
    for (int i = 0; i < 4; ++i) {
      const int qr = i + 8 * g + 4 * h;    // C-row for reg r = 4g+i
      const float invq = __shfl(inv, i + 8 * g + 4 * h, 64);
      const size_t row = (size_t)bh * S + qrow0 + qr;
      out[row * HD + lq]      = oacc[0][4 * g + i] * invq;
      out[row * HD + 32 + lq] = oacc[1][4 * g + i] * invq;
    }
}

extern "C" void kernel_launch(void* const* d_in, const int* in_sizes, int n_in,
                              void* d_out, int out_size, void* d_ws, size_t ws_size,
                              hipStream_t stream) {
  const float* query = (const float*)d_in[0];
  const float* W     = (const float*)d_in[1];
  const float* bias  = (const float*)d_in[2];
  float* out = (float*)d_out;
  char* ws = (char*)d_ws;

  float*          qkv = (float*)ws;                          // dead after stats_k
  // fp16 split planes live only between split_k and gemm_mfma:
  unsigned short* A1 = (unsigned short*)(ws + 50331648);
  unsigned short* A2 = (unsigned short*)(ws + 58720256);
  unsigned short* W1 = (unsigned short*)(ws + 67108864);
  unsigned short* W2 = (unsigned short*)(ws + 73400320);
  // stats outputs reuse the (dead) split region:
  unsigned short* qhi = (unsigned short*)(ws + 50331648);
  unsigned short* qlo = (unsigned short*)(ws + 58720256);
  unsigned short* khi = (unsigned short*)(ws + 67108864);
  unsigned short* klo = (unsigned short*)(ws + 75497472);
  unsigned short* vt  = (unsigned short*)(ws + 83886080);
  float*          rsb = (float*)(ws + 92274688);

  split_k  <<<dim3(7168), 256, 0, stream>>>(query, W, A1, A2, W1, W2);
  gemm_mfma<<<dim3(24, 32), 256, 0, stream>>>(A1, A2, W1, W2, bias, qkv);
  stats_k  <<<dim3(32, 32), 256, 0, stream>>>(qkv, qhi, qlo, khi, klo, vt, rsb);
  attn_k   <<<dim3(512), 256, 0, stream>>>(qhi, qlo, khi, klo, vt, rsb, out);
}

// Round 13
// 185.852 us; speedup vs baseline: 1.1696x; 1.0246x over previous
//
#include <hip/hip_runtime.h>

#define S 2048
#define D 1024
#define NH 16
#define HD 64
#define N3 3072         // 3 * D
#define M 4096          // T * B

typedef short s16x8 __attribute__((ext_vector_type(8)));
typedef _Float16 f16x8 __attribute__((ext_vector_type(8)));
typedef float f32x4 __attribute__((ext_vector_type(4)));
typedef float f32x16 __attribute__((ext_vector_type(16)));
typedef unsigned int u32;
typedef u32 u32x4 __attribute__((ext_vector_type(4)));

__device__ __forceinline__ unsigned short f2bf(float f) {
  unsigned u = __builtin_bit_cast(unsigned, f);
  u += 0x7fffu + ((u >> 16) & 1u);
  return (unsigned short)(u >> 16);
}
__device__ __forceinline__ float bf2f(unsigned short h) {
  return __builtin_bit_cast(float, (unsigned)h << 16);
}
__device__ __forceinline__ unsigned short f2h(float f) {
  _Float16 h = (_Float16)f;
  return __builtin_bit_cast(unsigned short, h);
}

__device__ __forceinline__ float wsum(float v) {
  #pragma unroll
  for (int m = 1; m < 64; m <<= 1) v += __shfl_xor(v, m, 64);
  return v;
}

__device__ __forceinline__ void gload_lds16(const unsigned short* g, unsigned short* l) {
  __builtin_amdgcn_global_load_lds(
      (const __attribute__((address_space(1))) u32*)g,
      (__attribute__((address_space(3))) u32*)l, 16, 0, 0);
}
__device__ __forceinline__ void gload_lds4(const float* g, float* l) {
  __builtin_amdgcn_global_load_lds(
      (const __attribute__((address_space(1))) u32*)g,
      (__attribute__((address_space(3))) u32*)l, 4, 0, 0);
}

// ---------------------------------------------------------------------------
// Kernel 0: split f32 -> 2x fp16 limbs (verified r4).
// ---------------------------------------------------------------------------
__global__ __launch_bounds__(256) void split_k(const float* __restrict__ q,
                                               const float* __restrict__ w,
                                               unsigned short* __restrict__ A1,
                                               unsigned short* __restrict__ A2,
                                               unsigned short* __restrict__ W1,
                                               unsigned short* __restrict__ W2) {
  const size_t gid = (size_t)blockIdx.x * 256 + threadIdx.x;   // quad index
  const size_t NA = (size_t)M * D / 4;                          // 1048576
  float4 x;
  unsigned short* p1; unsigned short* p2; size_t qi; float scale;
  if (gid < NA) {
    qi = gid;  x = ((const float4*)q)[qi];
    p1 = A1; p2 = A2; scale = 64.f;
  } else {
    qi = gid - NA;  x = ((const float4*)w)[qi];
    p1 = W1; p2 = W2; scale = 1024.f;
  }
  float e[4] = {x.x * scale, x.y * scale, x.z * scale, x.w * scale};
  unsigned short h1[4], h2[4];
  #pragma unroll
  for (int i = 0; i < 4; ++i) {
    _Float16 a = (_Float16)e[i];
    float r = e[i] - (float)a;
    _Float16 b = (_Float16)r;
    h1[i] = __builtin_bit_cast(unsigned short, a);
    h2[i] = __builtin_bit_cast(unsigned short, b);
  }
  *(ushort4*)&p1[qi * 4] = make_ushort4(h1[0], h1[1], h1[2], h1[3]);
  *(ushort4*)&p2[qi * 4] = make_ushort4(h2[0], h2[1], h2[2], h2[3]);
}

// ---------------------------------------------------------------------------
// Kernel 1: emulated-f32 GEMM on fp16 MFMA (verified r4, unchanged).
// ---------------------------------------------------------------------------
__global__ __launch_bounds__(256) void gemm_mfma(const unsigned short* __restrict__ A1,
                                                 const unsigned short* __restrict__ A2,
                                                 const unsigned short* __restrict__ W1,
                                                 const unsigned short* __restrict__ W2,
                                                 const float* __restrict__ bias,
                                                 float* __restrict__ C) {
  __shared__ unsigned short As[128 * 64];
  __shared__ unsigned short Bs[128 * 64];
  const int tid = threadIdx.x;
  const int w = tid >> 6, l = tid & 63;
  const int lo = l & 15, hi = l >> 4;
  const int n0 = blockIdx.x * 128, m0 = blockIdx.y * 128;
  const int wr = w >> 1, wc = w & 1;          // wave tile 64x64

  const int nseg = (n0 >= 2048) ? 1 : 3;

  const int srow = (tid >> 3) & 31;
  const int skc = tid & 7;

  f32x4 acc[4][4];
  #pragma unroll
  for (int mi = 0; mi < 4; ++mi)
    #pragma unroll
    for (int nj = 0; nj < 4; ++nj) acc[mi][nj] = (f32x4){0.f, 0.f, 0.f, 0.f};

  for (int s = 0; s < 3; ++s) {
    if (s >= nseg) break;
    const unsigned short* Ab;
    const unsigned short* Bb;
    switch (s) {                               // uniform scalar branch
      case 0: Ab = A1; Bb = W1; break;
      case 1: Ab = A2; Bb = W1; break;
      default: Ab = A1; Bb = W2; break;
    }
    Ab += (size_t)m0 * D;
    Bb += (size_t)n0 * D;

    for (int k0 = 0; k0 < D; k0 += 64) {
      __syncthreads();                         // prior iter's LDS reads done
      #pragma unroll
      for (int c = 0; c < 4; ++c) {
        const int row = c * 32 + srow;
        const int koct = skc ^ (row & 7);      // pre-swizzled source
        gload_lds16(Ab + (size_t)row * D + k0 + koct * 8,
                    As + c * 2048 + w * 512);
        gload_lds16(Bb + (size_t)row * D + k0 + koct * 8,
                    Bs + c * 2048 + w * 512);
      }
      __syncthreads();

      f16x8 af[4][2], bf[4][2];
      #pragma unroll
      for (int mi = 0; mi < 4; ++mi)
        #pragma unroll
        for (int ks = 0; ks < 2; ++ks) {
          const int row = wr * 64 + mi * 16 + lo;
          const int koct = (ks * 4 + hi) ^ (lo & 7);
          af[mi][ks] = *(const f16x8*)&As[row * 64 + koct * 8];
        }
      #pragma unroll
      for (int nj = 0; nj < 4; ++nj)
        #pragma unroll
        for (int ks = 0; ks < 2; ++ks) {
          const int row = wc * 64 + nj * 16 + lo;
          const int koct = (ks * 4 + hi) ^ (lo & 7);
          bf[nj][ks] = *(const f16x8*)&Bs[row * 64 + koct * 8];
        }
      #pragma unroll
      for (int mi = 0; mi < 4; ++mi)
        #pragma unroll
        for (int nj = 0; nj < 4; ++nj)
          #pragma unroll
          for (int ks = 0; ks < 2; ++ks)
            acc[mi][nj] = __builtin_amdgcn_mfma_f32_16x16x32_f16(
                af[mi][ks], bf[nj][ks], acc[mi][nj], 0, 0, 0);
    }
  }

  #pragma unroll
  for (int mi = 0; mi < 4; ++mi)
    #pragma unroll
    for (int nj = 0; nj < 4; ++nj) {
      const int n = n0 + wc * 64 + nj * 16 + lo;
      const float bj = bias[n];
      #pragma unroll
      for (int r = 0; r < 4; ++r) {
        const int m = m0 + wr * 64 + mi * 16 + hi * 4 + r;
        C[(size_t)m * N3 + n] = acc[mi][nj][r] * (1.f / 65536.f) + bj;
      }
    }
}

// ---------------------------------------------------------------------------
// Kernel 2: per-row stats + layout conversion (r9-exact numerics, verified
// absmax 9.77e-4): unfolded bf16 2-limb qc/kc; plain rs (no exp2 prescale);
// fp16 V.
// ---------------------------------------------------------------------------
__global__ __launch_bounds__(256) void stats_k(const float* __restrict__ qkv,
                                               unsigned short* __restrict__ qhi,
                                               unsigned short* __restrict__ qlo,
                                               unsigned short* __restrict__ khi,
                                               unsigned short* __restrict__ klo,
                                               unsigned short* __restrict__ vt,
                                               float* __restrict__ rs) {
  __shared__ unsigned short VsT[64][65];
  const int tt = blockIdx.x, bh = blockIdx.y;
  const int b = bh >> 4, h = bh & 15;
  const int w = threadIdx.x >> 6, l = threadIdx.x & 63;

  for (int rr = 0; rr < 16; ++rr) {
    const int t = tt * 64 + w * 16 + rr;
    const size_t base = (size_t)(t * 2 + b) * N3 + h * HD;
    const float q = qkv[base + l];
    const float k = qkv[base + D + l];
    const float v = qkv[base + 2 * D + l];
    const float qm = wsum(q) * (1.f / 64.f);
    const float km = wsum(k) * (1.f / 64.f);
    const float qcv = q - qm, kcv = k - km;
    const float d = wsum(qcv * kcv);
    float rv = 0.f;
    if (d > 0.f) {
      rv = rsqrtf(d);
      rv = rv * (1.5f - 0.5f * d * rv * rv);   // one NR step
    }
    const size_t ro = ((size_t)bh * S + t) * HD + l;
    const unsigned short qh = f2bf(qcv);
    const unsigned short kh = f2bf(kcv);
    qhi[ro] = qh;  qlo[ro] = f2bf(qcv - bf2f(qh));
    khi[ro] = kh;  klo[ro] = f2bf(kcv - bf2f(kh));
    if (l == 0) rs[(size_t)bh * S + t] = rv;
    VsT[l][w * 16 + rr] = f2h(v);              // fp16 V
  }
  __syncthreads();
  const int dd = threadIdx.x >> 2, seg = threadIdx.x & 3;
  unsigned pk[8];
  #pragma unroll
  for (int e = 0; e < 8; ++e) {
    unsigned l2 = VsT[dd][seg * 16 + 2 * e];
    unsigned h2 = VsT[dd][seg * 16 + 2 * e + 1];
    pk[e] = l2 | (h2 << 16);
  }
  unsigned short* dst = vt + ((size_t)bh * HD + dd) * S + tt * 64 + seg * 16;
  *(uint4*)dst       = make_uint4(pk[0], pk[1], pk[2], pk[3]);
  *(uint4*)(dst + 8) = make_uint4(pk[4], pk[5], pk[6], pk[7]);
}

// ---------------------------------------------------------------------------
// Kernel 3: fused correlation-softmax-PV, 32x32x16 swapped QK^T.
// r13 = r9's verified compute body (byte-identical math: __expf, clip +-1,
// unscaled rs) + TRUE async pipeline (catalog T3+T4): 2-deep prefetch with
// raw s_barrier + counted s_waitcnt vmcnt(7) (one 7-op STAGE stays in
// flight across the barrier; never drain to 0 until the last tile).
// Correctness: vmcnt is FIFO (m135) -> vmcnt(7) retires each wave's OLDEST
// stage; barrier #1 then makes tile t's writes visible to all. Barrier #2
// after compute: every wave's ds_reads of buf were consumed (feeding MFMAs
// can't issue without compiler lgkmcnt) before the buf is re-staged.
// Rsl staged redundantly by all waves -> wave-uniform VMEM count.
// + T5 setprio around compute (2 independent blocks/CU).
// ---------------------------------------------------------------------------
__global__ __launch_bounds__(256) void attn_k(const unsigned short* __restrict__ qhi,
                                              const unsigned short* __restrict__ qlo,
                                              const unsigned short* __restrict__ khi,
                                              const unsigned short* __restrict__ klo,
                                              const unsigned short* __restrict__ vt,
                                              const float* __restrict__ rs,
                                              float* __restrict__ out) {
  __shared__ unsigned short Kh[2 * 4096];  // [buf][row j][64 d], XOR-granule
  __shared__ unsigned short Kl[2 * 4096];
  __shared__ unsigned short Vsm[2 * 4096]; // [buf][row d][64 j], XOR-granule
  __shared__ float Rsl[2 * 64];

  const int tid = threadIdx.x;
  const int w = tid >> 6, l = tid & 63;
  const int lq = l & 31;                   // col q / A-row index
  const int h = l >> 5;                    // k-half selector
  const int l7 = l & 7;

  // T1: XCD-aware swizzle (512 = 8 XCD x 64, exact -> bijective).
  const int wgid = blockIdx.x;
  const int orig = (wgid & 7) * 64 + (wgid >> 3);
  const int bh = orig >> 4, qt = orig & 15;

  const unsigned short* qhb = qhi + (size_t)bh * S * HD;
  const unsigned short* qlb = qlo + (size_t)bh * S * HD;
  const unsigned short* khb = khi + (size_t)bh * S * HD;
  const unsigned short* klb = klo + (size_t)bh * S * HD;
  const unsigned short* vbase = vt + (size_t)bh * HD * S;
  const float* rbase = rs + (size_t)bh * S;
  const int qrow0 = qt * 128 + w * 32;     // wave owns 32 q-rows

  // staging map: linear LDS dest, pre-swizzled source (r9-verified)
  const int srow3 = l >> 3;                // 0..7 (row within wave's 8)
  const int sg = l7 ^ srow3;               // source granule

  // Q fragments (B-operand): lane holds q-row qrow0+lq, d-chunk kc*16+h*8
  s16x8 qfh[4], qfl[4];
  #pragma unroll
  for (int kc = 0; kc < 4; ++kc) {
    const size_t off = (size_t)(qrow0 + lq) * HD + kc * 16 + h * 8;
    qfh[kc] = *(const s16x8*)(qhb + off);
    qfl[kc] = *(const s16x8*)(qlb + off);
  }
  const float rsq = rbase[qrow0 + lq];     // lane-local row scale (q = lq)

  f32x16 oacc[2];
  oacc[0] = (f32x16)(0.f);
  oacc[1] = (f32x16)(0.f);
  float den = 0.f;

  // async stage of tile j0 into buffer buf: 7 VMEM ops per wave (uniform)
  auto STAGE = [&](int buf, int j0) {
    #pragma unroll
    for (int c = 0; c < 2; ++c) {
      const int row = c * 32 + w * 8 + srow3;
      const int dst = buf * 4096 + c * 2048 + w * 512;  // wave-uniform base
      gload_lds16(khb + (size_t)(j0 + row) * HD + sg * 8, Kh + dst);
      gload_lds16(klb + (size_t)(j0 + row) * HD + sg * 8, Kl + dst);
      gload_lds16(vbase + (size_t)row * S + j0 + sg * 8, Vsm + dst);
    }
    gload_lds4(rbase + j0 + l, Rsl + buf * 64);   // all waves, same data
  };

  STAGE(0, 0);
  STAGE(1, 64);

  for (int t = 0; t < 32; ++t) {
    // wait for tile t (oldest in-flight STAGE); keep tile t+1 in flight
    if (t < 31) asm volatile("s_waitcnt vmcnt(7)" ::: "memory");
    else        asm volatile("s_waitcnt vmcnt(0)" ::: "memory");
    __builtin_amdgcn_s_barrier();            // everyone's tile-t writes done
    __builtin_amdgcn_sched_barrier(0);

    const int cur = t & 1;
    const int cb = cur * 4096;               // current buffer base (shorts)

    __builtin_amdgcn_s_setprio(1);
    #pragma unroll
    for (int jblk = 0; jblk < 2; ++jblk) {
      // swapped QK^T: sacc[r] = S[j = 64t+jblk*32+(r&3)+8*(r>>2)+4h][q = lq]
      f32x16 sacc = (f32x16)(0.f);
      #pragma unroll
      for (int kc = 0; kc < 4; ++kc) {
        const int off = cb + (jblk * 32 + lq) * 64 + (((kc * 2 + h) ^ l7) << 3);
        s16x8 akh = *(const s16x8*)&Kh[off];
        s16x8 akl = *(const s16x8*)&Kl[off];
        sacc = __builtin_amdgcn_mfma_f32_32x32x16_bf16(akh, qfh[kc], sacc, 0, 0, 0);
        sacc = __builtin_amdgcn_mfma_f32_32x32x16_bf16(akl, qfh[kc], sacc, 0, 0, 0);
        sacc = __builtin_amdgcn_mfma_f32_32x32x16_bf16(akh, qfl[kc], sacc, 0, 0, 0);
      }

      // softmax elements + fp16 packs (pk[g] covers regs 4g..4g+3)
      u32 pkA[4], pkB[4];
      #pragma unroll
      for (int g = 0; g < 4; ++g) {
        f32x4 rjv = *(const f32x4*)&Rsl[cur * 64 + jblk * 32 + g * 8 + h * 4];
        float e0, e1, e2, e3;
        {
          float c0 = fminf(1.f, fmaxf(-1.f, sacc[4 * g + 0] * rsq * rjv[0]));
          float c1 = fminf(1.f, fmaxf(-1.f, sacc[4 * g + 1] * rsq * rjv[1]));
          float c2 = fminf(1.f, fmaxf(-1.f, sacc[4 * g + 2] * rsq * rjv[2]));
          float c3 = fminf(1.f, fmaxf(-1.f, sacc[4 * g + 3] * rsq * rjv[3]));
          e0 = __expf(c0); e1 = __expf(c1); e2 = __expf(c2); e3 = __expf(c3);
        }
        den += (e0 + e1) + (e2 + e3);
        pkA[g] = __builtin_bit_cast(u32, __builtin_amdgcn_cvt_pkrtz(e0, e1));
        pkB[g] = __builtin_bit_cast(u32, __builtin_amdgcn_cvt_pkrtz(e2, e3));
      }

      // P A-frags per k-chunk jc2 (j = (jblk*2+jc2)*16 + h*8 + 0..7)
      #pragma unroll
      for (int jc2 = 0; jc2 < 2; ++jc2) {
        const u32 sA = h ? pkA[2 * jc2] : pkA[2 * jc2 + 1];
        const u32 sB = h ? pkB[2 * jc2] : pkB[2 * jc2 + 1];
        const u32 rA = (u32)__shfl_xor((int)sA, 32, 64);
        const u32 rB = (u32)__shfl_xor((int)sB, 32, 64);
        u32x4 uu;
        uu[0] = h ? rA : pkA[2 * jc2];         // e0,e1 (low lane's group)
        uu[1] = h ? rB : pkB[2 * jc2];         // e2,e3
        uu[2] = h ? pkA[2 * jc2 + 1] : rA;     // e4,e5 (high lane's group)
        uu[3] = h ? pkB[2 * jc2 + 1] : rB;     // e6,e7
        const f16x8 pa = __builtin_bit_cast(f16x8, uu);

        const int jcg = jblk * 2 + jc2;
        #pragma unroll
        for (int dblk = 0; dblk < 2; ++dblk) {
          const int voff = cb + (dblk * 32 + lq) * 64 + (((jcg * 2 + h) ^ l7) << 3);
          f16x8 bv = *(const f16x8*)&Vsm[voff];
          oacc[dblk] = __builtin_amdgcn_mfma_f32_32x32x16_f16(pa, bv, oacc[dblk], 0, 0, 0);
        }
      }
    }
    __builtin_amdgcn_s_setprio(0);

    __builtin_amdgcn_sched_barrier(0);
    __builtin_amdgcn_s_barrier();            // all waves done reading cur
    __builtin_amdgcn_sched_barrier(0);
    if (t + 2 < 32) STAGE(cur, (t + 2) * 64);  // refill freed buffer (async)
  }

  // epilogue: den (this lane covers its h/reg j-subset; partner the rest)
  const float dtot = den + __shfl_xor(den, 32, 64);
  const float inv = 1.f / dtot;            // valid for q = lq (both halves)

  #pragma unroll
  for (int g = 0; g < 4; ++g)
    #pragma unroll
    for (int i = 0; i < 4; ++i) {
      const int qr = i + 8 * g + 4 * h;    // C-row for reg r = 4g+i
      const float invq = __shfl(inv, i + 8 * g + 4 * h, 64);
      const size_t row = (size_t)bh * S + qrow0 + qr;
      out[row * HD + lq]      = oacc[0][4 * g + i] * invq;
      out[row * HD + 32 + lq] = oacc[1][4 * g + i] * invq;
    }
}

extern "C" void kernel_launch(void* const* d_in, const int* in_sizes, int n_in,
                              void* d_out, int out_size, void* d_ws, size_t ws_size,
                              hipStream_t stream) {
  const float* query = (const float*)d_in[0];
  const float* W     = (const float*)d_in[1];
  const float* bias  = (const float*)d_in[2];
  float* out = (float*)d_out;
  char* ws = (char*)d_ws;

  float*          qkv = (float*)ws;                          // dead after stats_k
  // fp16 split planes live only between split_k and gemm_mfma:
  unsigned short* A1 = (unsigned short*)(ws + 50331648);
  unsigned short* A2 = (unsigned short*)(ws + 58720256);
  unsigned short* W1 = (unsigned short*)(ws + 67108864);
  unsigned short* W2 = (unsigned short*)(ws + 73400320);
  // stats outputs reuse the (dead) split region:
  unsigned short* qhi = (unsigned short*)(ws + 50331648);
  unsigned short* qlo = (unsigned short*)(ws + 58720256);
  unsigned short* khi = (unsigned short*)(ws + 67108864);
  unsigned short* klo = (unsigned short*)(ws + 75497472);
  unsigned short* vt  = (unsigned short*)(ws + 83886080);
  float*          rsb = (float*)(ws + 92274688);

  split_k  <<<dim3(7168), 256, 0, stream>>>(query, W, A1, A2, W1, W2);
  gemm_mfma<<<dim3(24, 32), 256, 0, stream>>>(A1, A2, W1, W2, bias, qkv);
  stats_k  <<<dim3(32, 32), 256, 0, stream>>>(qkv, qhi, qlo, khi, klo, vt, rsb);
  attn_k   <<<dim3(512), 256, 0, stream>>>(qhi, qlo, khi, klo, vt, rsb, out);
}